// Round 12
// baseline (6131.248 us; speedup 1.0000x reference)
//
#include <hip/hip_runtime.h>
#include <cstdint>
#include <cstddef>

#define T_STEPS 2048
#define BATCH 64

typedef _Float16 f16;
typedef _Float16 f16x2 __attribute__((ext_vector_type(2)));
typedef _Float16 f16x8 __attribute__((ext_vector_type(8)));
typedef float f32x4 __attribute__((ext_vector_type(4)));
typedef unsigned int uint32;
typedef uint32 u32x4 __attribute__((ext_vector_type(4)));

__device__ __forceinline__ float dot2(uint32 w, uint32 h, float c) {
  f16x2 a = __builtin_bit_cast(f16x2, w);
  f16x2 b = __builtin_bit_cast(f16x2, h);
  return __builtin_amdgcn_fdot2(a, b, c, false);
}

__device__ __forceinline__ float dot8(u32x4 w, u32x4 h, float c) {
  c = dot2(w[0], h[0], c);
  c = dot2(w[1], h[1], c);
  c = dot2(w[2], h[2], c);
  c = dot2(w[3], h[3], c);
  return c;
}

__device__ __forceinline__ uint32 pack2(f16 a, f16 b) {
  f16x2 t; t[0] = a; t[1] = b;
  return __builtin_bit_cast(uint32, t);
}

// ---------------------------------------------------------------- setup ----
// whp layout: [kq 0..31][out 0..1023][c 0..3] u32 (f16 pair each) --
// consecutive outs are 16B apart -> thread tid reads whp[kq*4096 + tid*4 ..]
// as one coalesced dwordx4.
__global__ __launch_bounds__(256) void setup_weights(
    const float* __restrict__ Wf, const float* __restrict__ Wi,
    const float* __restrict__ Wo, const float* __restrict__ Wc,
    const float* __restrict__ Wout,
    f16* __restrict__ wx16, f16* __restrict__ wout16, uint32* __restrict__ whp)
{
  int id = blockIdx.x * 256 + threadIdx.x;
  const float* WG_[4] = {Wf, Wi, Wo, Wc};
  if (id < 262144) {                       // WxAll f16 [1024][256] (x-part cols)
    int n = id >> 8, k = id & 255;
    int G = n >> 8, j = n & 255;
    wx16[id] = (f16)WG_[G][j * 512 + k];
    return;
  }
  id -= 262144;
  if (id < 65536) { wout16[id] = (f16)Wout[id]; return; }   // Wout f16 [256][256]
  id -= 65536;
  if (id < 131072) {                       // whp: packed f16 h-weights
    int kq = id >> 12, rem = id & 4095;
    int o = rem >> 2, c = rem & 3;
    int G = o >> 8, j = o & 255;
    const float* src = WG_[G] + j * 512 + 256 + kq * 8 + c * 2;
    whp[id] = pack2((f16)src[0], (f16)src[1]);
  }
}

__global__ __launch_bounds__(256) void setup_state(
    const float* __restrict__ h0, const float* __restrict__ C0,
    f16* __restrict__ hstate, float* __restrict__ c32)
{
  int id = blockIdx.x * 256 + threadIdx.x;
  if (id < 16384) { hstate[id] = (f16)h0[id]; return; }
  id -= 16384;
  if (id < 16384) c32[id] = C0[id];
}

// ---------------------------------------------------------------- GEMM -----
// C[M,N] = A[M,256] @ B[N,256]^T ; 128x128 tile, whole K staged, f16 MFMA.
template<int A_F32, int OUT_F32_BIAS>
__global__ __launch_bounds__(256) void gemm_k(
    const void* __restrict__ Av, const f16* __restrict__ B,
    void* __restrict__ Cv, const float* __restrict__ bias, int N)
{
  constexpr int LDA = 264;
  __shared__ f16 As[128 * 264];
  __shared__ f16 Bs[128 * 264];
  const int tid = threadIdx.x;
  const int m0 = blockIdx.x * 128;
  const int n0 = blockIdx.y * 128;

  if (A_F32) {
    const float* A = (const float*)Av;
    #pragma unroll
    for (int j = 0; j < 32; ++j) {
      int flat = (tid + j * 256) * 4;
      int row = flat >> 8, col = flat & 255;
      const float4 v = *(const float4*)(A + (size_t)(m0 + row) * 256 + col);
      uint2 u; u.x = pack2((f16)v.x, (f16)v.y); u.y = pack2((f16)v.z, (f16)v.w);
      *(uint2*)&As[row * LDA + col] = u;
    }
  } else {
    const f16* A = (const f16*)Av;
    #pragma unroll
    for (int j = 0; j < 32; ++j) {
      int flat = (tid + j * 256) * 4;
      int row = flat >> 8, col = flat & 255;
      *(uint2*)&As[row * LDA + col] = *(const uint2*)(A + (size_t)(m0 + row) * 256 + col);
    }
  }
  #pragma unroll
  for (int j = 0; j < 32; ++j) {
    int flat = (tid + j * 256) * 4;
    int row = flat >> 8, col = flat & 255;
    *(uint2*)&Bs[row * LDA + col] = *(const uint2*)(B + (size_t)(n0 + row) * 256 + col);
  }
  __syncthreads();

  const int wave = tid >> 6, l = tid & 63;
  const int wr = wave >> 1, wc = wave & 1;
  const int lr = l & 15, lq = l >> 4;

  f32x4 acc[4][4] = {};
  #pragma unroll
  for (int kk = 0; kk < 8; ++kk) {
    f16x8 a[4], b[4];
    #pragma unroll
    for (int mi = 0; mi < 4; ++mi)
      a[mi] = *(const f16x8*)&As[(64 * wr + 16 * mi + lr) * LDA + kk * 32 + lq * 8];
    #pragma unroll
    for (int ni = 0; ni < 4; ++ni)
      b[ni] = *(const f16x8*)&Bs[(64 * wc + 16 * ni + lr) * LDA + kk * 32 + lq * 8];
    #pragma unroll
    for (int mi = 0; mi < 4; ++mi)
      #pragma unroll
      for (int ni = 0; ni < 4; ++ni)
        acc[mi][ni] = __builtin_amdgcn_mfma_f32_16x16x32_f16(a[mi], b[ni], acc[mi][ni], 0, 0, 0);
  }

  #pragma unroll
  for (int mi = 0; mi < 4; ++mi) {
    #pragma unroll
    for (int ni = 0; ni < 4; ++ni) {
      int col = n0 + 64 * wc + 16 * ni + lr;
      float bv = 0.f;
      if (OUT_F32_BIAS) bv = bias[col];
      #pragma unroll
      for (int v = 0; v < 4; ++v) {
        int row = m0 + 64 * wr + 16 * mi + lq * 4 + v;
        if (OUT_F32_BIAS) ((float*)Cv)[(size_t)row * N + col] = acc[mi][ni][v] + bv;
        else              ((f16*)Cv)[(size_t)row * N + col] = (f16)acc[mi][ni][v];
      }
    }
  }
}

// --------------------------------------------------------- persistent LSTM -
// 64 WGs x 1024 thr; WG r owns batch row r ENTIRELY -> zero cross-WG traffic.
// Thread (G=tid>>8, jj=tid&255) owns ONE gate output, K=256 = 32 K-quads of
// PRE-PACKED f16 weights (whp): 8 named VGPR quads (32 regs, fits the
// observed 64-reg budget for 1024-thr WGs) + 9 quads LDS-resident (147KB)
// + 15 quads streamed from XCD-L2 each step (pure dwordx4 loads, zero
// repack VALU -- R11's loss was f32 reload + in-loop f16 packing).
// h in 512B LDS updated in place; C in registers; two barriers/step.
#define RL8(M) M(0) M(1) M(2) M(3) M(4) M(5) M(6) M(7)

__global__ __launch_bounds__(1024) void lstm_persist(
    const uint32* __restrict__ whp,
    const float* __restrict__ bf, const float* __restrict__ bi,
    const float* __restrict__ bo, const float* __restrict__ bc,
    const f16* __restrict__ xproj, f16* __restrict__ hstate,
    float* __restrict__ c32, float* __restrict__ hid_out,
    f16* __restrict__ h16c, float* __restrict__ cf_out, int t0, int Tc)
{
  __shared__ u32x4 wtail[9 * 1024];                          // 147456B tail
  __shared__ uint32 h_lds[128] __attribute__((aligned(16))); // h (256 f16)
  __shared__ float part[4 * 260];                            // padded pre-acts

  const int tid = threadIdx.x;
  const int r = blockIdx.x;
  const int G = tid >> 8, jj = tid & 255;   // G is wave-uniform

  const float* bGp = (G == 0) ? bf : (G == 1) ? bi : (G == 2) ? bo : bc;
  const u32x4* wq = (const u32x4*)whp;      // [kq*1024 + out]

  // ---- one-time: kq 0..7 named regs, kq 23..31 into LDS ----
#define LOADW(i) u32x4 w##i = wq[(i) * 1024 + tid];
  RL8(LOADW)
#undef LOADW
  #pragma unroll
  for (int i = 0; i < 9; ++i) wtail[i * 1024 + tid] = wq[(23 + i) * 1024 + tid];

  const float biasv = bGp[jj];

  float Creg = 0.f;
  if (tid < 256) Creg = c32[r * 256 + tid];
  if (tid < 128) h_lds[tid] = ((const uint32*)hstate)[r * 128 + tid];
  __syncthreads();

  for (int tl = 0; tl < Tc; ++tl) {
    const int gt = t0 + tl;

    // x-projection load issues here, consumed at the end of the dot chain
    const float xpv = (float)xproj[((size_t)tl * 64 + r) * 1024 + (G << 8) + jj];

    // opaque tid: keeps streamed/LDS reads inside the loop (no hoist->spill)
    int otid;
    asm volatile("v_mov_b32 %0, %1" : "=v"(otid) : "v"(tid));

    float acc = 0.f;
    // named-register quads (kq 0..7)
#define DOTW(i) { const u32x4 hh = *(const u32x4*)&h_lds[(i) * 4]; \
                  acc = dot8(w##i, hh, acc); }
    RL8(DOTW)
#undef DOTW
    // L2-streamed quads (kq 8..22): coalesced dwordx4, no repacking
    #pragma unroll
    for (int kq = 8; kq < 23; ++kq) {
      const u32x4 hh = *(const u32x4*)&h_lds[kq * 4];
      const u32x4 wv = wq[kq * 1024 + otid];
      acc = dot8(wv, hh, acc);
    }
    // LDS-resident quads (kq 23..31)
    #pragma unroll
    for (int i = 0; i < 9; ++i) {
      const u32x4 hh = *(const u32x4*)&h_lds[(23 + i) * 4];
      acc = dot8(wtail[i * 1024 + otid], hh, acc);
    }

    part[G * 260 + jj] = acc + xpv + biasv;
    __syncthreads();

    // pointwise update: thread tid<256 owns column j=tid
    if (tid < 256) {
      const float pf = part[tid];
      const float pi = part[260 + tid];
      const float po = part[520 + tid];
      const float pc = part[780 + tid];
      const float f_ = __builtin_amdgcn_rcpf(1.f + __expf(-pf));
      const float i_ = __builtin_amdgcn_rcpf(1.f + __expf(-pi));
      const float o_ = __builtin_amdgcn_rcpf(1.f + __expf(-po));
      const float cb = 1.f - 2.f * __builtin_amdgcn_rcpf(__expf(2.f * pc) + 1.f);
      const float Cn = f_ * Creg + i_ * cb;
      Creg = Cn;
      const float th = 1.f - 2.f * __builtin_amdgcn_rcpf(__expf(2.f * Cn) + 1.f);
      const float hn = o_ * th;
      hid_out[((size_t)gt * 64 + r) * 256 + tid] = hn;
      const f16 h16v = (f16)hn;
      ((unsigned short*)h_lds)[tid] = __builtin_bit_cast(unsigned short, h16v);
      h16c[((size_t)tl * 64 + r) * 256 + tid] = h16v;
      if (gt == T_STEPS - 1) cf_out[r * 256 + tid] = Cn;
    }
    __syncthreads();
  }

  if (tid < 256) c32[r * 256 + tid] = Creg;
  if (tid < 128) ((uint32*)hstate)[r * 128 + tid] = h_lds[tid];
}

// ---------------------------------------------------------------- host -----
extern "C" void kernel_launch(void* const* d_in, const int* in_sizes, int n_in,
                              void* d_out, int out_size, void* d_ws, size_t ws_size,
                              hipStream_t stream)
{
  const float* x    = (const float*)d_in[0];
  const float* h0   = (const float*)d_in[1];
  const float* C0   = (const float*)d_in[2];
  const float* Wf   = (const float*)d_in[3];
  const float* bf   = (const float*)d_in[4];
  const float* Wi   = (const float*)d_in[5];
  const float* bi   = (const float*)d_in[6];
  const float* Wo   = (const float*)d_in[7];
  const float* bo   = (const float*)d_in[8];
  const float* Wc   = (const float*)d_in[9];
  const float* bc   = (const float*)d_in[10];
  const float* Wout = (const float*)d_in[11];
  const float* bout = (const float*)d_in[12];
  float* out = (float*)d_out;

  char* w = (char*)d_ws;
  f16*    wx16   = (f16*)w;    w += (size_t)1024 * 256 * 2;
  f16*    wout16 = (f16*)w;    w += (size_t)256 * 256 * 2;
  uint32* whp    = (uint32*)w; w += (size_t)131072 * 4;
  f16*    hstate = (f16*)w;    w += (size_t)64 * 256 * 2;
  float*  c32    = (float*)w;  w += (size_t)64 * 256 * 4;
  const size_t fixedB = (size_t)(w - (char*)d_ws);

  int Tc = 2;
  const int cands[] = {2048, 1024, 512, 256, 128, 64, 32, 16, 8, 4, 2};
  for (int c : cands) {
    if (fixedB + (size_t)c * 163840 <= ws_size) { Tc = c; break; }
  }

  f16* xproj = (f16*)w;
  f16* h16c  = (f16*)(w + (size_t)Tc * 64 * 1024 * 2);

  setup_weights<<<1792, 256, 0, stream>>>(Wf, Wi, Wo, Wc, Wout,
                                          wx16, wout16, whp);
  setup_state<<<128, 256, 0, stream>>>(h0, C0, hstate, c32);

  float* hid_out = out + (size_t)T_STEPS * 64 * 256;
  float* cf_out  = out + (size_t)2 * T_STEPS * 64 * 256;

  for (int t0 = 0; t0 < T_STEPS; t0 += Tc) {
    gemm_k<1, 0><<<dim3(Tc * 64 / 128, 8), 256, 0, stream>>>(
        x + (size_t)t0 * 64 * 256, wx16, xproj, nullptr, 1024);
    lstm_persist<<<64, 1024, 0, stream>>>(whp, bf, bi, bo, bc,
                                          xproj, hstate, c32,
                                          hid_out, h16c, cf_out, t0, Tc);
    gemm_k<0, 1><<<dim3(Tc * 64 / 128, 2), 256, 0, stream>>>(
        h16c, wout16, out + (size_t)t0 * 64 * 256, bout, 256);
  }
}

// Round 14
// 3711.182 us; speedup vs baseline: 1.6521x; 1.6521x over previous
//
#include <hip/hip_runtime.h>
#include <cstdint>
#include <cstddef>

#define T_STEPS 2048
#define BATCH 64

typedef _Float16 f16;
typedef _Float16 f16x2 __attribute__((ext_vector_type(2)));
typedef _Float16 f16x8 __attribute__((ext_vector_type(8)));
typedef float f32x4 __attribute__((ext_vector_type(4)));
typedef unsigned int uint32;
typedef unsigned long long uint64;
typedef uint32 u32x4 __attribute__((ext_vector_type(4)));

__device__ __forceinline__ float dot2(uint32 w, uint32 h, float c) {
  f16x2 a = __builtin_bit_cast(f16x2, w);
  f16x2 b = __builtin_bit_cast(f16x2, h);
  return __builtin_amdgcn_fdot2(a, b, c, false);
}

__device__ __forceinline__ float dot8(u32x4 w, u32x4 h, float c) {
  c = dot2(w[0], h[0], c);
  c = dot2(w[1], h[1], c);
  c = dot2(w[2], h[2], c);
  c = dot2(w[3], h[3], c);
  return c;
}

__device__ __forceinline__ uint32 pack2(f16 a, f16 b) {
  f16x2 t; t[0] = a; t[1] = b;
  return __builtin_bit_cast(uint32, t);
}

// ---------------------------------------------------------------- setup ----
// whp layout: [kq 0..31][out 0..1023][c 0..3] u32 (f16 pair) -- thread with
// output o reads whp[kq*4096 + o*4 ..] as one coalesced dwordx4.
__global__ __launch_bounds__(256) void setup_weights(
    const float* __restrict__ Wf, const float* __restrict__ Wi,
    const float* __restrict__ Wo, const float* __restrict__ Wc,
    const float* __restrict__ Wout,
    f16* __restrict__ wx16, f16* __restrict__ wout16, uint32* __restrict__ whp)
{
  int id = blockIdx.x * 256 + threadIdx.x;
  const float* WG_[4] = {Wf, Wi, Wo, Wc};
  if (id < 262144) {                       // WxAll f16 [1024][256] (x-part cols)
    int n = id >> 8, k = id & 255;
    int G = n >> 8, j = n & 255;
    wx16[id] = (f16)WG_[G][j * 512 + k];
    return;
  }
  id -= 262144;
  if (id < 65536) { wout16[id] = (f16)Wout[id]; return; }   // Wout f16 [256][256]
  id -= 65536;
  if (id < 131072) {                       // whp: packed f16 h-weights
    int kq = id >> 12, rem = id & 4095;
    int o = rem >> 2, c = rem & 3;
    int G = o >> 8, j = o & 255;
    const float* src = WG_[G] + j * 512 + 256 + kq * 8 + c * 2;
    whp[id] = pack2((f16)src[0], (f16)src[1]);
  }
}

// hpair: [parity 2][slot 128 = r*2+hf][64 u64]; parity0 = tag0|h0,
// parity1 = sentinel 0xFFFF tags.
__global__ __launch_bounds__(256) void setup_state(
    const float* __restrict__ h0, const float* __restrict__ C0,
    uint64* __restrict__ hpair, float* __restrict__ c32)
{
  int id = blockIdx.x * 256 + threadIdx.x;
  if (id < 8192) {
    int slot = id >> 6, i = id & 63;
    int r = slot >> 1, hf = slot & 1;
    const float* hr = h0 + r * 256 + hf * 128 + 2 * i;
    uint32 a = (uint32)__builtin_bit_cast(unsigned short, (f16)hr[0]);
    uint32 b = (uint32)__builtin_bit_cast(unsigned short, (f16)hr[1]);
    hpair[id] = ((uint64)b << 32) | (uint64)a;
    return;
  }
  id -= 8192;
  if (id < 8192) { hpair[8192 + id] = 0xFFFF0000FFFF0000ULL; return; }
  id -= 8192;
  if (id < 16384) c32[id] = C0[id];
}

// ---------------------------------------------------------------- GEMM -----
template<int A_F32, int OUT_F32_BIAS>
__global__ __launch_bounds__(256) void gemm_k(
    const void* __restrict__ Av, const f16* __restrict__ B,
    void* __restrict__ Cv, const float* __restrict__ bias, int N)
{
  constexpr int LDA = 264;
  __shared__ f16 As[128 * 264];
  __shared__ f16 Bs[128 * 264];
  const int tid = threadIdx.x;
  const int m0 = blockIdx.x * 128;
  const int n0 = blockIdx.y * 128;

  if (A_F32) {
    const float* A = (const float*)Av;
    #pragma unroll
    for (int j = 0; j < 32; ++j) {
      int flat = (tid + j * 256) * 4;
      int row = flat >> 8, col = flat & 255;
      const float4 v = *(const float4*)(A + (size_t)(m0 + row) * 256 + col);
      uint2 u; u.x = pack2((f16)v.x, (f16)v.y); u.y = pack2((f16)v.z, (f16)v.w);
      *(uint2*)&As[row * LDA + col] = u;
    }
  } else {
    const f16* A = (const f16*)Av;
    #pragma unroll
    for (int j = 0; j < 32; ++j) {
      int flat = (tid + j * 256) * 4;
      int row = flat >> 8, col = flat & 255;
      *(uint2*)&As[row * LDA + col] = *(const uint2*)(A + (size_t)(m0 + row) * 256 + col);
    }
  }
  #pragma unroll
  for (int j = 0; j < 32; ++j) {
    int flat = (tid + j * 256) * 4;
    int row = flat >> 8, col = flat & 255;
    *(uint2*)&Bs[row * LDA + col] = *(const uint2*)(B + (size_t)(n0 + row) * 256 + col);
  }
  __syncthreads();

  const int wave = tid >> 6, l = tid & 63;
  const int wr = wave >> 1, wc = wave & 1;
  const int lr = l & 15, lq = l >> 4;

  f32x4 acc[4][4] = {};
  #pragma unroll
  for (int kk = 0; kk < 8; ++kk) {
    f16x8 a[4], b[4];
    #pragma unroll
    for (int mi = 0; mi < 4; ++mi)
      a[mi] = *(const f16x8*)&As[(64 * wr + 16 * mi + lr) * LDA + kk * 32 + lq * 8];
    #pragma unroll
    for (int ni = 0; ni < 4; ++ni)
      b[ni] = *(const f16x8*)&Bs[(64 * wc + 16 * ni + lr) * LDA + kk * 32 + lq * 8];
    #pragma unroll
    for (int mi = 0; mi < 4; ++mi)
      #pragma unroll
      for (int ni = 0; ni < 4; ++ni)
        acc[mi][ni] = __builtin_amdgcn_mfma_f32_16x16x32_f16(a[mi], b[ni], acc[mi][ni], 0, 0, 0);
  }

  #pragma unroll
  for (int mi = 0; mi < 4; ++mi) {
    #pragma unroll
    for (int ni = 0; ni < 4; ++ni) {
      int col = n0 + 64 * wc + 16 * ni + lr;
      float bv = 0.f;
      if (OUT_F32_BIAS) bv = bias[col];
      #pragma unroll
      for (int v = 0; v < 4; ++v) {
        int row = m0 + 64 * wr + 16 * mi + lq * 4 + v;
        if (OUT_F32_BIAS) ((float*)Cv)[(size_t)row * N + col] = acc[mi][ni][v] + bv;
        else              ((f16*)Cv)[(size_t)row * N + col] = (f16)acc[mi][ni][v];
      }
    }
  }
}

// --------------------------------------------------------- persistent LSTM -
// R14 = R13's weight residency + R7's EXACT exchange skeleton (the one that
// passed post-timing replay validation). 128 WGs x 512 thr; WG = (row r,
// half hf). Thread owns one gate output (G, j=hf*128+jjl), full K=256:
// 16 own-half + 4 sibling quads in named VGPRs (80 regs) + 12 sibling quads
// in 96KB LDS -> zero in-loop global weight traffic.
// Per iteration (R7 order): spin(top, sibling half; tl==0 also own half) ->
// barrier -> dots -> barrier -> pointwise (writes hstage) -> barrier ->
// publish own half from hstage (fire-and-forget tagged u64 atomics) + local
// h_lds own-half update. Parity ping-pong, tag-in-data validation.
#define RLO16(M) M(0) M(1) M(2) M(3) M(4) M(5) M(6) M(7) M(8) M(9) M(10) M(11) \
  M(12) M(13) M(14) M(15)
#define RLS4(M) M(0) M(1) M(2) M(3)

__global__ __launch_bounds__(512) void lstm_persist(
    const uint32* __restrict__ whp,
    const float* __restrict__ bf, const float* __restrict__ bi,
    const float* __restrict__ bo, const float* __restrict__ bc,
    const f16* __restrict__ xproj, uint64* __restrict__ hpair,
    float* __restrict__ c32, float* __restrict__ hid_out,
    f16* __restrict__ h16c, float* __restrict__ cf_out, int t0, int Tc)
{
  __shared__ u32x4 wlds[12 * 512];                           // 96KB LDS quads
  __shared__ uint32 h_lds[128] __attribute__((aligned(16))); // full h (256 f16)
  __shared__ float part[4 * 132];                            // padded pre-acts
  __shared__ unsigned short hstage[128];                     // new own-half h

  const int tid = threadIdx.x;
  const int w = blockIdx.x;
  const int hf  = (w >> 3) & 1;                // sibling = w ^ 8 (same XCD)
  const int r   = (w & 7) | ((w >> 4) << 3);   // r in [0,64)
  const int G = tid >> 7, jjl = tid & 127;
  const int j = hf * 128 + jjl;                // global column
  const int o = (G << 8) + j;                  // whp output index

  const int hfo = hf * 64;                     // own-half h_lds base (u32)
  const int sfo = (hf ^ 1) * 64;               // sibling-half base
  const int okq = hf * 16;                     // own-half first K-quad
  const int skq = (hf ^ 1) * 16;               // sibling first K-quad

  const u32x4* wq = (const u32x4*)whp;         // [kq*1024 + o]

  // ---- one-time: 16 own + 4 sib quads in regs, 12 sib quads in LDS ----
#define LOADO(i) u32x4 wo##i = wq[(okq + (i)) * 1024 + o];
  RLO16(LOADO)
#undef LOADO
#define LOADS(i) u32x4 ws##i = wq[(skq + (i)) * 1024 + o];
  RLS4(LOADS)
#undef LOADS
  #pragma unroll
  for (int i = 0; i < 12; ++i)
    wlds[i * 512 + tid] = wq[(skq + 4 + i) * 1024 + o];

  const float* bGp = (G == 0) ? bf : (G == 1) ? bi : (G == 2) ? bo : bc;
  const float biasv = bGp[j];

  float Creg = 0.f;
  if (tid < 128) Creg = c32[r * 256 + j];

  uint64* mybuf  = hpair + (size_t)(r * 2 + hf) * 64;
  uint64* sibbuf = hpair + (size_t)(r * 2 + (hf ^ 1)) * 64;

  for (int tl = 0; tl < Tc; ++tl) {
    const int gt = t0 + tl;
    const int pp = gt & 1;

    // A: x-projection load (hides under the spin)
    const float xpv = (float)xproj[((size_t)tl * 64 + r) * 1024 + o];

    // B: fill h_lds. Sibling half: tag-validated spin (tid<64). Own half:
    // maintained by phase H, except at tl==0 where threads 64..127 load it.
    if (tid < 64) {
      const uint64* p = sibbuf + (size_t)pp * 8192 + tid;
      const uint32 tg = (uint32)gt;
      uint64 v = __hip_atomic_load(p, __ATOMIC_RELAXED, __HIP_MEMORY_SCOPE_AGENT);
      int tries = 0;
      while (((((uint32)v) >> 16) != tg || ((uint32)(v >> 48)) != tg) &&
             ++tries < (1 << 22)) {
        v = __hip_atomic_load(p, __ATOMIC_RELAXED, __HIP_MEMORY_SCOPE_AGENT);
      }
      h_lds[sfo + tid] =
          (((uint32)v) & 0xFFFFu) | ((((uint32)(v >> 32)) & 0xFFFFu) << 16);
    } else if (tl == 0 && tid < 128) {
      const int i = tid - 64;
      const uint64* p = mybuf + (size_t)pp * 8192 + i;
      const uint32 tg = (uint32)gt;
      uint64 v = __hip_atomic_load(p, __ATOMIC_RELAXED, __HIP_MEMORY_SCOPE_AGENT);
      int tries = 0;
      while (((((uint32)v) >> 16) != tg || ((uint32)(v >> 48)) != tg) &&
             ++tries < (1 << 22)) {
        v = __hip_atomic_load(p, __ATOMIC_RELAXED, __HIP_MEMORY_SCOPE_AGENT);
      }
      h_lds[hfo + i] =
          (((uint32)v) & 0xFFFFu) | ((((uint32)(v >> 32)) & 0xFFFFu) << 16);
    }
    __syncthreads();  // C

    // D: full-K dot chain (own 16 reg quads + sib 4 reg + 12 LDS quads)
    int otid;
    asm volatile("v_mov_b32 %0, %1" : "=v"(otid) : "v"(tid));
    float acc = 0.f;
#define DOT_O(i) { const u32x4 hh = *(const u32x4*)&h_lds[hfo + (i) * 4]; \
                   acc = dot8(wo##i, hh, acc); }
    RLO16(DOT_O)
#undef DOT_O
#define DOT_S(i) { const u32x4 hh = *(const u32x4*)&h_lds[sfo + (i) * 4]; \
                   acc = dot8(ws##i, hh, acc); }
    RLS4(DOT_S)
#undef DOT_S
    #pragma unroll
    for (int i = 0; i < 12; ++i) {
      const u32x4 hh = *(const u32x4*)&h_lds[sfo + (4 + i) * 4];
      acc = dot8(wlds[i * 512 + otid], hh, acc);
    }
    part[G * 132 + jjl] = acc + xpv + biasv;
    __syncthreads();  // E

    // F: pointwise update (tid<128 owns column j) -> hstage
    if (tid < 128) {
      const float pf = part[tid];
      const float pi = part[132 + tid];
      const float po = part[264 + tid];
      const float pc = part[396 + tid];
      const float f_ = __builtin_amdgcn_rcpf(1.f + __expf(-pf));
      const float i_ = __builtin_amdgcn_rcpf(1.f + __expf(-pi));
      const float o_ = __builtin_amdgcn_rcpf(1.f + __expf(-po));
      const float cb = 1.f - 2.f * __builtin_amdgcn_rcpf(__expf(2.f * pc) + 1.f);
      const float Cn = f_ * Creg + i_ * cb;
      Creg = Cn;
      const float th = 1.f - 2.f * __builtin_amdgcn_rcpf(__expf(2.f * Cn) + 1.f);
      const float hn = o_ * th;
      hid_out[((size_t)gt * 64 + r) * 256 + j] = hn;
      const f16 h16v = (f16)hn;
      hstage[tid] = __builtin_bit_cast(unsigned short, h16v);
      h16c[((size_t)tl * 64 + r) * 256 + j] = h16v;
      if (gt == T_STEPS - 1) cf_out[r * 256 + j] = Cn;
    }
    __syncthreads();  // G

    // H: publish own half (fire-and-forget tagged u64 atomics) + local h_lds
    if (tid < 64) {
      const uint32 a = (uint32)hstage[2 * tid];
      const uint32 b = (uint32)hstage[2 * tid + 1];
      h_lds[hfo + tid] = a | (b << 16);
      const uint32 tg1u = ((uint32)(gt + 1)) << 16;
      const uint64 v = ((uint64)(b | tg1u) << 32) | (uint64)(a | tg1u);
      __hip_atomic_store(mybuf + (size_t)((gt + 1) & 1) * 8192 + tid, v,
                         __ATOMIC_RELAXED, __HIP_MEMORY_SCOPE_AGENT);
    }
  }

  if (tid < 128) c32[r * 256 + j] = Creg;
}

// ---------------------------------------------------------------- host -----
extern "C" void kernel_launch(void* const* d_in, const int* in_sizes, int n_in,
                              void* d_out, int out_size, void* d_ws, size_t ws_size,
                              hipStream_t stream)
{
  const float* x    = (const float*)d_in[0];
  const float* h0   = (const float*)d_in[1];
  const float* C0   = (const float*)d_in[2];
  const float* Wf   = (const float*)d_in[3];
  const float* bf   = (const float*)d_in[4];
  const float* Wi   = (const float*)d_in[5];
  const float* bi   = (const float*)d_in[6];
  const float* Wo   = (const float*)d_in[7];
  const float* bo   = (const float*)d_in[8];
  const float* Wc   = (const float*)d_in[9];
  const float* bc   = (const float*)d_in[10];
  const float* Wout = (const float*)d_in[11];
  const float* bout = (const float*)d_in[12];
  float* out = (float*)d_out;

  char* w = (char*)d_ws;
  f16*    wx16   = (f16*)w;    w += (size_t)1024 * 256 * 2;
  f16*    wout16 = (f16*)w;    w += (size_t)256 * 256 * 2;
  uint32* whp    = (uint32*)w; w += (size_t)131072 * 4;
  uint64* hpair  = (uint64*)w; w += (size_t)2 * 8192 * 8;
  float*  c32    = (float*)w;  w += (size_t)64 * 256 * 4;
  const size_t fixedB = (size_t)(w - (char*)d_ws);

  int Tc = 2;
  const int cands[] = {2048, 1024, 512, 256, 128, 64, 32, 16, 8, 4, 2};
  for (int c : cands) {
    if (fixedB + (size_t)c * 163840 <= ws_size) { Tc = c; break; }
  }

  f16* xproj = (f16*)w;
  f16* h16c  = (f16*)(w + (size_t)Tc * 64 * 1024 * 2);

  setup_weights<<<1792, 256, 0, stream>>>(Wf, Wi, Wo, Wc, Wout,
                                          wx16, wout16, whp);
  setup_state<<<128, 256, 0, stream>>>(h0, C0, hpair, c32);

  float* hid_out = out + (size_t)T_STEPS * 64 * 256;
  float* cf_out  = out + (size_t)2 * T_STEPS * 64 * 256;

  for (int t0 = 0; t0 < T_STEPS; t0 += Tc) {
    gemm_k<1, 0><<<dim3(Tc * 64 / 128, 8), 256, 0, stream>>>(
        x + (size_t)t0 * 64 * 256, wx16, xproj, nullptr, 1024);
    lstm_persist<<<128, 512, 0, stream>>>(whp, bf, bi, bo, bc,
                                          xproj, hpair, c32,
                                          hid_out, h16c, cf_out, t0, Tc);
    gemm_k<0, 1><<<dim3(Tc * 64 / 128, 2), 256, 0, stream>>>(
        h16c, wout16, out + (size_t)t0 * 64 * 256, bout, 256);
  }
}